// Round 5
// baseline (194.237 us; speedup 1.0000x reference)
//
#include <hip/hip_runtime.h>
#include <hip/hip_cooperative_groups.h>
#include <math.h>

namespace cg = cooperative_groups;

// B=8, C=128, H=W=64, HW=4096, c8=16, c2=64, pooled J=1024
#define HW 4096
#define SHIFT 12.0f   // exact softmax invariant; keeps exp in fp32/bf16 range

typedef __attribute__((ext_vector_type(4)))  short short4v;
typedef __attribute__((ext_vector_type(8)))  short short8;
typedef __attribute__((ext_vector_type(4)))  float f32x4;
typedef __attribute__((ext_vector_type(16))) float f32x16;
typedef __attribute__((ext_vector_type(4)))  int   int4v;

#define MFMA16 __builtin_amdgcn_mfma_f32_16x16x32_bf16
#define MFMA32 __builtin_amdgcn_mfma_f32_32x32x16_bf16

__device__ inline short f2b(float f) {   // fp32 -> bf16 RNE
    union { float f; unsigned u; } v; v.f = f;
    unsigned r = v.u + 0x7fffu + ((v.u >> 16) & 1u);
    return (short)(r >> 16);
}
__device__ inline int pk2(float a, float b) {  // pack 2 bf16 (a=low)
    return (int)((unsigned)(unsigned short)f2b(a) |
                 ((unsigned)(unsigned short)f2b(b) << 16));
}
__device__ inline short8 ld8(const float* p) { // 8 contiguous fp32 -> bf16x8
    f32x4 a = *(const f32x4*)p;
    f32x4 b = *(const f32x4*)(p + 4);
    short8 r;
    r[0] = f2b(a.x); r[1] = f2b(a.y); r[2] = f2b(a.z); r[3] = f2b(a.w);
    r[4] = f2b(b.x); r[5] = f2b(b.y); r[6] = f2b(b.z); r[7] = f2b(b.w);
    return r;
}
__device__ inline float max4(float a, float b, float c, float d) {
    return fmaxf(fmaxf(a, b), fmaxf(c, d));
}

// ---------------------------------------------------------------------------
// Phase 1: fused 1x1 convs + 2x2 maxpool. Block bid = (b, rp, h): rows
// {2rp,2rp+1}, cols [32h,32h+32) -> 64 px. x staged bf16 LDS [128c][68];
// weights converted inline from fp32 (L2-broadcast across blocks).
// Wave w: pair p=w&1 (px chunks {p, p+2} -> pool partners same wave),
// cs group csbase=(w>>1)*3. Writes theta_t[i][16], phi_t[j][16],
// g_blk[((b*64+jb)*64+c)*16+jl] bf16 (j = jb*16+jl).
__device__ void phase1(const float* __restrict__ x, const float* __restrict__ wt,
                       const float* __restrict__ wp, const float* __restrict__ wg,
                       short* __restrict__ theta_t, short* __restrict__ phi_t,
                       short* __restrict__ g_blk, char* smem, int bid)
{
    short* xl = (short*)smem;                 // [128][68]
    const int tid = threadIdx.x;
    const int w = tid >> 6, lane = tid & 63, l15 = lane & 15, lg = (lane >> 4) & 3;
    const int b = bid >> 6, ri = bid & 63, rp = ri >> 1, h = ri & 1;
    const float* xb = x + (size_t)b * 128 * HW + rp * 128 + h * 32;

    for (int it = 0; it < 8; it++) {          // 2048 float4s
        int idx = it * 256 + tid;
        int c = idx >> 4, q = idx & 15;
        int px4 = q * 4, r = px4 >> 5, col4 = px4 & 31;
        f32x4 v = *(const f32x4*)(xb + (size_t)c * HW + r * 64 + col4);
        short4v sv = { f2b(v.x), f2b(v.y), f2b(v.z), f2b(v.w) };
        *(short4v*)(xl + c * 68 + px4) = sv;
    }
    __syncthreads();

    const int p = w & 1, csbase = (w >> 1) * 3;
    f32x4 acc[2][3];
#pragma unroll
    for (int cc = 0; cc < 2; cc++)
#pragma unroll
        for (int cl = 0; cl < 3; cl++) acc[cc][cl] = (f32x4){0.f, 0.f, 0.f, 0.f};

#pragma unroll
    for (int ks = 0; ks < 4; ks++) {
        short8 a[2];
#pragma unroll
        for (int cc = 0; cc < 2; cc++) {
            int px = (p + 2 * cc) * 16 + l15;
#pragma unroll
            for (int q = 0; q < 8; q++)
                a[cc][q] = xl[(ks * 32 + lg * 8 + q) * 68 + px];
        }
#pragma unroll
        for (int csl = 0; csl < 3; csl++) {
            int cs = csbase + csl;
            const float* wrow;
            if (cs == 0)      wrow = wt + l15 * 128;
            else if (cs == 1) wrow = wp + l15 * 128;
            else              wrow = wg + ((cs - 2) * 16 + l15) * 128;
            short8 bf = ld8(wrow + ks * 32 + lg * 8);
            acc[0][csl] = MFMA16(a[0], bf, acc[0][csl], 0, 0, 0);
            acc[1][csl] = MFMA16(a[1], bf, acc[1][csl], 0, 0, 0);
        }
    }

    const size_t pixb = (size_t)b * 4096 + rp * 128 + h * 32 + p * 16;
#pragma unroll
    for (int csl = 0; csl < 3; csl++) {
        int cs = csbase + csl;
        if (cs == 0) {            // theta: C rows = px-in-chunk
#pragma unroll
            for (int cc = 0; cc < 2; cc++)
#pragma unroll
                for (int r = 0; r < 4; r++)
                    theta_t[(pixb + cc * 64 + lg * 4 + r) * 16 + l15] =
                        f2b(acc[cc][csl][r]);
        } else if (cs == 1) {     // phi pool
#pragma unroll
            for (int h2 = 0; h2 < 2; h2++) {
                float m = max4(acc[0][csl][2 * h2], acc[0][csl][2 * h2 + 1],
                               acc[1][csl][2 * h2], acc[1][csl][2 * h2 + 1]);
                int j = rp * 32 + h * 16 + p * 8 + lg * 2 + h2;
                phi_t[((size_t)b * 1024 + j) * 16 + l15] = f2b(m);
            }
        } else {                  // g pool, blocked layout
            int gcrow = (cs - 2) * 16 + l15;
            float m0 = max4(acc[0][csl][0], acc[0][csl][1], acc[1][csl][0], acc[1][csl][1]);
            float m1 = max4(acc[0][csl][2], acc[0][csl][3], acc[1][csl][2], acc[1][csl][3]);
            int jb = rp * 2 + h, jl = p * 8 + lg * 2;
            *(int*)(g_blk + (((size_t)b * 64 + jb) * 64 + gcrow) * 16 + jl) = pk2(m0, m1);
        }
    }
}

// ---------------------------------------------------------------------------
// Phase 2: attention (identical math to R4's passing attn_k; wo converted
// inline from fp32). Block bid = (b, 64 i's). Wave w: ihalf=w&1, jhalf=w>>1.
// Shift-softmax, S^T via MFMA32 (K=16 exact), P^T/O^T C->B-frag transform
// via shfl_xor(32) on packed bf16 pairs; static private indexing only.
__device__ void phase2(const float* __restrict__ x, const short* __restrict__ theta_t,
                       const short* __restrict__ phi_t, const short* __restrict__ g_blk,
                       const float* __restrict__ wo, const float* __restrict__ gamma_p,
                       float* __restrict__ out, char* smem, int bid)
{
    float* lds = (float*)smem;   // partials [w][cs2][reg][64] + l [w][64]
    const int tid = threadIdx.x;
    const int w = tid >> 6, lane = tid & 63, l31 = lane & 31, lam = lane >> 5;
    const int b = bid >> 6, i0 = (bid & 63) << 6;
    const int ihalf = w & 1, jhalf = w >> 1;
    const int i = i0 + ihalf * 32 + l31;

    short8 tb = *(const short8*)(theta_t + ((size_t)b * 4096 + i) * 16 + lam * 8);

    f32x16 acc0, acc1, z16;
#pragma unroll
    for (int r = 0; r < 16; r++) { acc0[r] = 0.f; acc1[r] = 0.f; z16[r] = 0.f; }
    float rs = 0.f;

    for (int t = 0; t < 8; t++) {
        const int jt = jhalf * 8 + t;
        f32x16 s0, s1;
        {
            short8 pa0 = *(const short8*)(phi_t + ((size_t)b * 1024 + jt * 64 + l31) * 16 + lam * 8);
            short8 pa1 = *(const short8*)(phi_t + ((size_t)b * 1024 + jt * 64 + 32 + l31) * 16 + lam * 8);
            s0 = MFMA32(pa0, tb, z16, 0, 0, 0);
            s1 = MFMA32(pa1, tb, z16, 0, 0, 0);
        }
        int W[16], X[16];
#pragma unroll
        for (int jk = 0; jk < 2; jk++)
#pragma unroll
            for (int rg = 0; rg < 4; rg++)
#pragma unroll
                for (int h = 0; h < 2; h++) {
                    float p0 = __expf((jk ? s1 : s0)[rg * 4 + 2 * h]     - SHIFT);
                    float p1 = __expf((jk ? s1 : s0)[rg * 4 + 2 * h + 1] - SHIFT);
                    rs += p0 + p1;
                    W[jk * 8 + rg * 2 + h] = pk2(p0, p1);
                }
#pragma unroll
        for (int k = 0; k < 16; k++) X[k] = __shfl_xor(W[k], 32, 64);

#pragma unroll
        for (int ck = 0; ck < 4; ck++) {
            const int cb2 = (ck >> 1) * 8 + (ck & 1) * 4;
            int4v pi;
            pi.x = lam ? X[cb2 + 2] : W[cb2];
            pi.y = lam ? X[cb2 + 3] : W[cb2 + 1];
            pi.z = lam ? W[cb2 + 2] : X[cb2];
            pi.w = lam ? W[cb2 + 3] : X[cb2 + 1];
            short8 pb = __builtin_bit_cast(short8, pi);
            const short* gp = g_blk + (((size_t)b * 64 + jt * 4 + ck) * 64) * 16;
            short8 ga0 = *(const short8*)(gp + (l31)      * 16 + lam * 8);
            short8 ga1 = *(const short8*)(gp + (32 + l31) * 16 + lam * 8);
            acc0 = MFMA32(ga0, pb, acc0, 0, 0, 0);
            acc1 = MFMA32(ga1, pb, acc1, 0, 0, 0);
        }
    }

    rs += __shfl_xor(rs, 32, 64);

#pragma unroll
    for (int reg = 0; reg < 16; reg++) {
        lds[((w * 2 + 0) * 16 + reg) * 64 + lane] = acc0[reg];
        lds[((w * 2 + 1) * 16 + reg) * 64 + lane] = acc1[reg];
    }
    lds[8192 + w * 64 + lane] = rs;
    __syncthreads();

    const int cbhalf = w >> 1;
    float o[32];
#pragma unroll
    for (int cs2 = 0; cs2 < 2; cs2++)
#pragma unroll
        for (int reg = 0; reg < 16; reg++)
            o[cs2 * 16 + reg] =
                lds[((ihalf       * 2 + cs2) * 16 + reg) * 64 + lane] +
                lds[(((2 + ihalf) * 2 + cs2) * 16 + reg) * 64 + lane];
    float lf = lds[8192 + ihalf * 64 + lane] + lds[8192 + (2 + ihalf) * 64 + lane];
    float rinv = 1.0f / lf;
#pragma unroll
    for (int k = 0; k < 32; k++) o[k] *= rinv;

    int Wo[16], Xo[16];
#pragma unroll
    for (int cs2 = 0; cs2 < 2; cs2++)
#pragma unroll
        for (int rg = 0; rg < 4; rg++)
#pragma unroll
            for (int h = 0; h < 2; h++)
                Wo[cs2 * 8 + rg * 2 + h] =
                    pk2(o[cs2 * 16 + rg * 4 + 2 * h], o[cs2 * 16 + rg * 4 + 2 * h + 1]);
#pragma unroll
    for (int k = 0; k < 16; k++) Xo[k] = __shfl_xor(Wo[k], 32, 64);

    const float gam = gamma_p[0];
#pragma unroll
    for (int cb = 0; cb < 2; cb++) {
        f32x16 oc;
#pragma unroll
        for (int r = 0; r < 16; r++) oc[r] = 0.f;
#pragma unroll
        for (int kc = 0; kc < 4; kc++) {
            const int cb2 = (kc >> 1) * 8 + (kc & 1) * 4;
            int4v pi;
            pi.x = lam ? Xo[cb2 + 2] : Wo[cb2];
            pi.y = lam ? Xo[cb2 + 3] : Wo[cb2 + 1];
            pi.z = lam ? Wo[cb2 + 2] : Xo[cb2];
            pi.w = lam ? Wo[cb2 + 3] : Xo[cb2 + 1];
            short8 ob = __builtin_bit_cast(short8, pi);
            short8 wa = ld8(wo + (size_t)(cbhalf * 64 + cb * 32 + l31) * 64 + kc * 16 + lam * 8);
            oc = MFMA32(wa, ob, oc, 0, 0, 0);
        }
#pragma unroll
        for (int reg = 0; reg < 16; reg++) {
            int co = cbhalf * 64 + cb * 32 + (reg & 3) + 8 * (reg >> 2) + 4 * lam;
            size_t idx = ((size_t)b * 128 + co) * HW + i0 + ihalf * 32 + l31;
            out[idx] = gam * oc[reg] + x[idx];
        }
    }
}

// ---------------------------------------------------------------------------
__global__ __launch_bounds__(256) void fused_k(
    const float* x, const float* wt, const float* wp, const float* wg,
    const float* wo, const float* gamma_p, float* out,
    short* theta_t, short* phi_t, short* g_blk)
{
    __shared__ __align__(16) char smem[33792];
    phase1(x, wt, wp, wg, theta_t, phi_t, g_blk, smem, blockIdx.x);
    cg::this_grid().sync();
    phase2(x, theta_t, phi_t, g_blk, wo, gamma_p, out, smem, blockIdx.x);
}

__global__ __launch_bounds__(256) void p1_k(
    const float* x, const float* wt, const float* wp, const float* wg,
    short* theta_t, short* phi_t, short* g_blk)
{
    __shared__ __align__(16) char smem[17408];
    phase1(x, wt, wp, wg, theta_t, phi_t, g_blk, smem, blockIdx.x);
}

__global__ __launch_bounds__(256) void p2_k(
    const float* x, const short* theta_t, const short* phi_t, const short* g_blk,
    const float* wo, const float* gamma_p, float* out)
{
    __shared__ __align__(16) char smem[33792];
    phase2(x, theta_t, phi_t, g_blk, wo, gamma_p, out, smem, blockIdx.x);
}

// ---------------------------------------------------------------------------
extern "C" void kernel_launch(void* const* d_in, const int* in_sizes, int n_in,
                              void* d_out, int out_size, void* d_ws, size_t ws_size,
                              hipStream_t stream)
{
    const float* x     = (const float*)d_in[0];
    const float* wt    = (const float*)d_in[1];
    const float* wp    = (const float*)d_in[2];
    const float* wg    = (const float*)d_in[3];
    const float* wo    = (const float*)d_in[4];
    const float* gamma = (const float*)d_in[5];
    float* out = (float*)d_out;

    char* ws = (char*)d_ws;
    short* theta_t = (short*)(ws + 0);        // 8*4096*16 sh = 1048576 B
    short* phi_t   = (short*)(ws + 1048576);  // 8*1024*16 sh = 262144 B
    short* g_blk   = (short*)(ws + 1310720);  // 8*64*64*16 sh = 1048576 B

    void* args[] = { (void*)&x, (void*)&wt, (void*)&wp, (void*)&wg, (void*)&wo,
                     (void*)&gamma, (void*)&out, (void*)&theta_t, (void*)&phi_t,
                     (void*)&g_blk };
    hipError_t rc = hipLaunchCooperativeKernel((const void*)fused_k,
                                               dim3(512), dim3(256), args, 0, stream);
    if (rc != hipSuccess) {
        (void)hipGetLastError();   // clear sticky error, fall back to 2 launches
        p1_k<<<512, 256, 0, stream>>>(x, wt, wp, wg, theta_t, phi_t, g_blk);
        p2_k<<<512, 256, 0, stream>>>(x, theta_t, phi_t, g_blk, wo, gamma, out);
    }
}

// Round 6
// 115.841 us; speedup vs baseline: 1.6768x; 1.6768x over previous
//
#include <hip/hip_runtime.h>
#include <math.h>

// B=8, C=128, H=W=64, HW=4096, c8=16, c2=64, pooled J=1024
#define HW 4096
#define SHIFT 12.0f   // exact softmax invariant; keeps exp in fp32/bf16 range

typedef __attribute__((ext_vector_type(4)))  short short4v;
typedef __attribute__((ext_vector_type(8)))  short short8;
typedef __attribute__((ext_vector_type(4)))  float f32x4;
typedef __attribute__((ext_vector_type(16))) float f32x16;
typedef __attribute__((ext_vector_type(4)))  int   int4v;

#define MFMA16 __builtin_amdgcn_mfma_f32_16x16x32_bf16
#define MFMA32 __builtin_amdgcn_mfma_f32_32x32x16_bf16

__device__ inline short f2b(float f) {   // fp32 -> bf16 RNE
    union { float f; unsigned u; } v; v.f = f;
    unsigned r = v.u + 0x7fffu + ((v.u >> 16) & 1u);
    return (short)(r >> 16);
}
__device__ inline int pk2(float a, float b) {  // pack 2 bf16 (a=low)
    return (int)((unsigned)(unsigned short)f2b(a) |
                 ((unsigned)(unsigned short)f2b(b) << 16));
}
__device__ inline short8 ld8(const float* p) { // 8 contiguous fp32 -> bf16x8
    f32x4 a = *(const f32x4*)p;
    f32x4 b = *(const f32x4*)(p + 4);
    short8 r;
    r[0] = f2b(a.x); r[1] = f2b(a.y); r[2] = f2b(a.z); r[3] = f2b(a.w);
    r[4] = f2b(b.x); r[5] = f2b(b.y); r[6] = f2b(b.z); r[7] = f2b(b.w);
    return r;
}
__device__ inline float max4(float a, float b, float c, float d) {
    return fmaxf(fmaxf(a, b), fmaxf(c, d));
}

// ---------------------------------------------------------------------------
// K1: fused 1x1 convs + 2x2 maxpool (inline fp32->bf16 weight conversion;
// weights are 64 KB, L2-broadcast across blocks -- no prep kernel).
// Block bid = (b, rp, h): rows {2rp,2rp+1}, cols [32h,32h+32) -> 64 px.
// x staged bf16 in LDS [128c][68]. Wave w: px-pair p=w&1 (chunks {p,p+2} so
// 2x2 pool partners live in the same thread's C-layout regs -> in-register
// pooling), cs group csbase=(w>>1)*3. Writes theta_t[i][16], phi_t[j][16],
// g_blk[((b*64+jb)*64+c)*16+jl] bf16 (j = jb*16+jl).
__global__ __launch_bounds__(256) void conv_pool(
    const float* __restrict__ x, const float* __restrict__ wt,
    const float* __restrict__ wp, const float* __restrict__ wg,
    short* __restrict__ theta_t, short* __restrict__ phi_t,
    short* __restrict__ g_blk)
{
    __shared__ __align__(16) short xl[128 * 68];
    const int tid = threadIdx.x;
    const int w = tid >> 6, lane = tid & 63, l15 = lane & 15, lg = (lane >> 4) & 3;
    const int bid = blockIdx.x;
    const int b = bid >> 6, ri = bid & 63, rp = ri >> 1, h = ri & 1;
    const float* xb = x + (size_t)b * 128 * HW + rp * 128 + h * 32;

    for (int it = 0; it < 8; it++) {          // 2048 float4s
        int idx = it * 256 + tid;
        int c = idx >> 4, q = idx & 15;
        int px4 = q * 4, r = px4 >> 5, col4 = px4 & 31;
        f32x4 v = *(const f32x4*)(xb + (size_t)c * HW + r * 64 + col4);
        short4v sv = { f2b(v.x), f2b(v.y), f2b(v.z), f2b(v.w) };
        *(short4v*)(xl + c * 68 + px4) = sv;
    }
    __syncthreads();

    const int p = w & 1, csbase = (w >> 1) * 3;
    f32x4 acc[2][3];
#pragma unroll
    for (int cc = 0; cc < 2; cc++)
#pragma unroll
        for (int cl = 0; cl < 3; cl++) acc[cc][cl] = (f32x4){0.f, 0.f, 0.f, 0.f};

#pragma unroll
    for (int ks = 0; ks < 4; ks++) {
        short8 a[2];
#pragma unroll
        for (int cc = 0; cc < 2; cc++) {
            int px = (p + 2 * cc) * 16 + l15;
#pragma unroll
            for (int q = 0; q < 8; q++)
                a[cc][q] = xl[(ks * 32 + lg * 8 + q) * 68 + px];
        }
#pragma unroll
        for (int csl = 0; csl < 3; csl++) {
            int cs = csbase + csl;
            const float* wrow;
            if (cs == 0)      wrow = wt + l15 * 128;
            else if (cs == 1) wrow = wp + l15 * 128;
            else              wrow = wg + ((cs - 2) * 16 + l15) * 128;
            short8 bf = ld8(wrow + ks * 32 + lg * 8);
            acc[0][csl] = MFMA16(a[0], bf, acc[0][csl], 0, 0, 0);
            acc[1][csl] = MFMA16(a[1], bf, acc[1][csl], 0, 0, 0);
        }
    }

    const size_t pixb = (size_t)b * 4096 + rp * 128 + h * 32 + p * 16;
#pragma unroll
    for (int csl = 0; csl < 3; csl++) {
        int cs = csbase + csl;
        if (cs == 0) {            // theta: C rows = px-in-chunk
#pragma unroll
            for (int cc = 0; cc < 2; cc++)
#pragma unroll
                for (int r = 0; r < 4; r++)
                    theta_t[(pixb + cc * 64 + lg * 4 + r) * 16 + l15] =
                        f2b(acc[cc][csl][r]);
        } else if (cs == 1) {     // phi pool
#pragma unroll
            for (int h2 = 0; h2 < 2; h2++) {
                float m = max4(acc[0][csl][2 * h2], acc[0][csl][2 * h2 + 1],
                               acc[1][csl][2 * h2], acc[1][csl][2 * h2 + 1]);
                int j = rp * 32 + h * 16 + p * 8 + lg * 2 + h2;
                phi_t[((size_t)b * 1024 + j) * 16 + l15] = f2b(m);
            }
        } else {                  // g pool, blocked layout
            int gcrow = (cs - 2) * 16 + l15;
            float m0 = max4(acc[0][csl][0], acc[0][csl][1], acc[1][csl][0], acc[1][csl][1]);
            float m1 = max4(acc[0][csl][2], acc[0][csl][3], acc[1][csl][2], acc[1][csl][3]);
            int jb = rp * 2 + h, jl = p * 8 + lg * 2;
            *(int*)(g_blk + (((size_t)b * 64 + jb) * 64 + gcrow) * 16 + jl) = pk2(m0, m1);
        }
    }
}

// ---------------------------------------------------------------------------
// K2: attention (R4's verified attn_k; wo converted inline from fp32).
// Block = (b, 64 i's). Wave w: ihalf=w&1 (32 i), jhalf=w>>1 (512 j).
// Shift-softmax (no running max; partials combine by plain add at the single
// epilogue barrier). QK: S^T = MFMA32(phi, theta), K=16 exact. C->B-frag
// transform for P^T / O^T crosses only lane bit5 -> shfl_xor(32) on packed
// bf16 pairs, no LDS in the j-loop, no barriers in the j-loop.
// NOTE: private arrays are only ever statically indexed (runtime `lam`
// selection via ternaries) -- dynamic indexing would demote them to scratch.
__global__ __launch_bounds__(256) void attn_k(
    const float* __restrict__ x, const short* __restrict__ theta_t,
    const short* __restrict__ phi_t, const short* __restrict__ g_blk,
    const float* __restrict__ wo, const float* __restrict__ gamma_p,
    float* __restrict__ out)
{
    __shared__ float lds[8192 + 256];   // partials [w][cs2][reg][64] + l [w][64]
    const int tid = threadIdx.x;
    const int w = tid >> 6, lane = tid & 63, l31 = lane & 31, lam = lane >> 5;
    const int b = blockIdx.x >> 6, i0 = (blockIdx.x & 63) << 6;
    const int ihalf = w & 1, jhalf = w >> 1;
    const int i = i0 + ihalf * 32 + l31;

    // persistent theta B-frag: B[n=i][k=c], k = lam*8+q (K=16 exact)
    short8 tb = *(const short8*)(theta_t + ((size_t)b * 4096 + i) * 16 + lam * 8);

    f32x16 acc0, acc1, z16;
#pragma unroll
    for (int r = 0; r < 16; r++) { acc0[r] = 0.f; acc1[r] = 0.f; z16[r] = 0.f; }
    float rs = 0.f;

    for (int t = 0; t < 8; t++) {
        const int jt = jhalf * 8 + t;
        // ---- QK: S^T[64j][32i], rows j = jk*32 + (reg&3)+8*(reg>>2)+4*lam
        f32x16 s0, s1;
        {
            short8 pa0 = *(const short8*)(phi_t + ((size_t)b * 1024 + jt * 64 + l31) * 16 + lam * 8);
            short8 pa1 = *(const short8*)(phi_t + ((size_t)b * 1024 + jt * 64 + 32 + l31) * 16 + lam * 8);
            s0 = MFMA32(pa0, tb, z16, 0, 0, 0);
            s1 = MFMA32(pa1, tb, z16, 0, 0, 0);
        }
        // ---- exp + pack pairs: W[jk*8+rg*2+h] covers j = 32jk+8rg+4lam+2h+{0,1}
        int W[16], X[16];
#pragma unroll
        for (int jk = 0; jk < 2; jk++)
#pragma unroll
            for (int rg = 0; rg < 4; rg++)
#pragma unroll
                for (int h = 0; h < 2; h++) {
                    float p0 = __expf((jk ? s1 : s0)[rg * 4 + 2 * h]     - SHIFT);
                    float p1 = __expf((jk ? s1 : s0)[rg * 4 + 2 * h + 1] - SHIFT);
                    rs += p0 + p1;
                    W[jk * 8 + rg * 2 + h] = pk2(p0, p1);
                }
#pragma unroll
        for (int k = 0; k < 16; k++) X[k] = __shfl_xor(W[k], 32, 64);

        // ---- PV: O^T[c][i] += G^T . P^T ; B-frag(ck): static idx + lam-cndmask
#pragma unroll
        for (int ck = 0; ck < 4; ck++) {
            const int cb2 = (ck >> 1) * 8 + (ck & 1) * 4;
            int4v pi;
            pi.x = lam ? X[cb2 + 2] : W[cb2];
            pi.y = lam ? X[cb2 + 3] : W[cb2 + 1];
            pi.z = lam ? W[cb2 + 2] : X[cb2];
            pi.w = lam ? W[cb2 + 3] : X[cb2 + 1];
            short8 pb = __builtin_bit_cast(short8, pi);
            const short* gp = g_blk + (((size_t)b * 64 + jt * 4 + ck) * 64) * 16;
            short8 ga0 = *(const short8*)(gp + (l31)      * 16 + lam * 8);
            short8 ga1 = *(const short8*)(gp + (32 + l31) * 16 + lam * 8);
            acc0 = MFMA32(ga0, pb, acc0, 0, 0, 0);
            acc1 = MFMA32(ga1, pb, acc1, 0, 0, 0);
        }
    }

    // ---- combine lane halves of row-sum (both halves hold same i=l31)
    rs += __shfl_xor(rs, 32, 64);

    // ---- write partials, one barrier, cross-jhalf combine
#pragma unroll
    for (int reg = 0; reg < 16; reg++) {
        lds[((w * 2 + 0) * 16 + reg) * 64 + lane] = acc0[reg];
        lds[((w * 2 + 1) * 16 + reg) * 64 + lane] = acc1[reg];
    }
    lds[8192 + w * 64 + lane] = rs;
    __syncthreads();

    // every wave rebuilds full O^T for its ihalf; splits co by cbhalf = w>>1
    const int cbhalf = w >> 1;
    float o[32];
#pragma unroll
    for (int cs2 = 0; cs2 < 2; cs2++)
#pragma unroll
        for (int reg = 0; reg < 16; reg++)
            o[cs2 * 16 + reg] =
                lds[((ihalf       * 2 + cs2) * 16 + reg) * 64 + lane] +
                lds[(((2 + ihalf) * 2 + cs2) * 16 + reg) * 64 + lane];
    float lf = lds[8192 + ihalf * 64 + lane] + lds[8192 + (2 + ihalf) * 64 + lane];
    float rinv = 1.0f / lf;
#pragma unroll
    for (int k = 0; k < 32; k++) o[k] *= rinv;

    // pack O^T rows c = cs2*32 + 8rg + 4lam + 2h+{0,1}; exchange lane halves
    int Wo[16], Xo[16];
#pragma unroll
    for (int cs2 = 0; cs2 < 2; cs2++)
#pragma unroll
        for (int rg = 0; rg < 4; rg++)
#pragma unroll
            for (int h = 0; h < 2; h++)
                Wo[cs2 * 8 + rg * 2 + h] =
                    pk2(o[cs2 * 16 + rg * 4 + 2 * h], o[cs2 * 16 + rg * 4 + 2 * h + 1]);
#pragma unroll
    for (int k = 0; k < 16; k++) Xo[k] = __shfl_xor(Wo[k], 32, 64);

    const float gam = gamma_p[0];
#pragma unroll
    for (int cb = 0; cb < 2; cb++) {
        f32x16 oc;
#pragma unroll
        for (int r = 0; r < 16; r++) oc[r] = 0.f;
#pragma unroll
        for (int kc = 0; kc < 4; kc++) {
            const int cb2 = (kc >> 1) * 8 + (kc & 1) * 4;
            int4v pi;
            pi.x = lam ? Xo[cb2 + 2] : Wo[cb2];
            pi.y = lam ? Xo[cb2 + 3] : Wo[cb2 + 1];
            pi.z = lam ? Wo[cb2 + 2] : Xo[cb2];
            pi.w = lam ? Wo[cb2 + 3] : Xo[cb2 + 1];
            short8 ob = __builtin_bit_cast(short8, pi);
            short8 wa = ld8(wo + (size_t)(cbhalf * 64 + cb * 32 + l31) * 64 + kc * 16 + lam * 8);
            oc = MFMA32(wa, ob, oc, 0, 0, 0);
        }
#pragma unroll
        for (int reg = 0; reg < 16; reg++) {
            int co = cbhalf * 64 + cb * 32 + (reg & 3) + 8 * (reg >> 2) + 4 * lam;
            size_t idx = ((size_t)b * 128 + co) * HW + i0 + ihalf * 32 + l31;
            out[idx] = gam * oc[reg] + x[idx];
        }
    }
}

// ---------------------------------------------------------------------------
extern "C" void kernel_launch(void* const* d_in, const int* in_sizes, int n_in,
                              void* d_out, int out_size, void* d_ws, size_t ws_size,
                              hipStream_t stream)
{
    const float* x     = (const float*)d_in[0];
    const float* wt    = (const float*)d_in[1];
    const float* wp    = (const float*)d_in[2];
    const float* wg    = (const float*)d_in[3];
    const float* wo    = (const float*)d_in[4];
    const float* gamma = (const float*)d_in[5];
    float* out = (float*)d_out;

    char* ws = (char*)d_ws;
    short* theta_t = (short*)(ws + 0);        // 8*4096*16 sh = 1048576 B
    short* phi_t   = (short*)(ws + 1048576);  // 8*1024*16 sh = 262144 B
    short* g_blk   = (short*)(ws + 1310720);  // 8*64*64*16 sh = 1048576 B
    // total ~2.25 MiB of workspace

    conv_pool<<<512, 256, 0, stream>>>(x, wt, wp, wg, theta_t, phi_t, g_blk);
    attn_k   <<<512, 256, 0, stream>>>(x, theta_t, phi_t, g_blk, wo, gamma, out);
}

// Round 7
// 103.111 us; speedup vs baseline: 1.8838x; 1.1235x over previous
//
#include <hip/hip_runtime.h>
#include <math.h>

// B=8, C=128, H=W=64, HW=4096, c8=16, c2=64, pooled J=1024
#define HW 4096
#define SHIFT 12.0f   // exact softmax invariant; keeps exp in fp32/bf16 range

typedef __attribute__((ext_vector_type(4)))  short short4v;
typedef __attribute__((ext_vector_type(8)))  short short8;
typedef __attribute__((ext_vector_type(4)))  float f32x4;
typedef __attribute__((ext_vector_type(16))) float f32x16;
typedef __attribute__((ext_vector_type(4)))  int   int4v;

#define MFMA16 __builtin_amdgcn_mfma_f32_16x16x32_bf16
#define MFMA32 __builtin_amdgcn_mfma_f32_32x32x16_bf16

__device__ inline short f2b(float f) {   // fp32 -> bf16 RNE
    union { float f; unsigned u; } v; v.f = f;
    unsigned r = v.u + 0x7fffu + ((v.u >> 16) & 1u);
    return (short)(r >> 16);
}
__device__ inline int pk2(float a, float b) {  // pack 2 bf16 (a=low)
    return (int)((unsigned)(unsigned short)f2b(a) |
                 ((unsigned)(unsigned short)f2b(b) << 16));
}
__device__ inline short8 ld8(const float* p) { // 8 contiguous fp32 -> bf16x8
    f32x4 a = *(const f32x4*)p;
    f32x4 b = *(const f32x4*)(p + 4);
    short8 r;
    r[0] = f2b(a.x); r[1] = f2b(a.y); r[2] = f2b(a.z); r[3] = f2b(a.w);
    r[4] = f2b(b.x); r[5] = f2b(b.y); r[6] = f2b(b.z); r[7] = f2b(b.w);
    return r;
}
__device__ inline float max4(float a, float b, float c, float d) {
    return fmaxf(fmaxf(a, b), fmaxf(c, d));
}

// ---------------------------------------------------------------------------
// K1: fused 1x1 convs + 2x2 maxpool (inline fp32->bf16 weight conversion).
// Block bid = (b, rp, h): rows {2rp,2rp+1}, cols [32h,32h+32) -> 64 px.
// x staged bf16 in LDS [128c][68]. Wave w: px-pair p=w&1 (chunks {p,p+2} so
// 2x2 pool partners live in the same thread's C-layout regs -> in-register
// pooling), cs group csbase=(w>>1)*3. Writes theta_t[i][16], phi_t[j][16],
// g_blk[((b*64+jb)*64+c)*16+jl] bf16 (j = jb*16+jl).
__global__ __launch_bounds__(256) void conv_pool(
    const float* __restrict__ x, const float* __restrict__ wt,
    const float* __restrict__ wp, const float* __restrict__ wg,
    short* __restrict__ theta_t, short* __restrict__ phi_t,
    short* __restrict__ g_blk)
{
    __shared__ __align__(16) short xl[128 * 68];
    const int tid = threadIdx.x;
    const int w = tid >> 6, lane = tid & 63, l15 = lane & 15, lg = (lane >> 4) & 3;
    const int bid = blockIdx.x;
    const int b = bid >> 6, ri = bid & 63, rp = ri >> 1, h = ri & 1;
    const float* xb = x + (size_t)b * 128 * HW + rp * 128 + h * 32;

    for (int it = 0; it < 8; it++) {          // 2048 float4s
        int idx = it * 256 + tid;
        int c = idx >> 4, q = idx & 15;
        int px4 = q * 4, r = px4 >> 5, col4 = px4 & 31;
        f32x4 v = *(const f32x4*)(xb + (size_t)c * HW + r * 64 + col4);
        short4v sv = { f2b(v.x), f2b(v.y), f2b(v.z), f2b(v.w) };
        *(short4v*)(xl + c * 68 + px4) = sv;
    }
    __syncthreads();

    const int p = w & 1, csbase = (w >> 1) * 3;
    f32x4 acc[2][3];
#pragma unroll
    for (int cc = 0; cc < 2; cc++)
#pragma unroll
        for (int cl = 0; cl < 3; cl++) acc[cc][cl] = (f32x4){0.f, 0.f, 0.f, 0.f};

#pragma unroll
    for (int ks = 0; ks < 4; ks++) {
        short8 a[2];
#pragma unroll
        for (int cc = 0; cc < 2; cc++) {
            int px = (p + 2 * cc) * 16 + l15;
#pragma unroll
            for (int q = 0; q < 8; q++)
                a[cc][q] = xl[(ks * 32 + lg * 8 + q) * 68 + px];
        }
#pragma unroll
        for (int csl = 0; csl < 3; csl++) {
            int cs = csbase + csl;
            const float* wrow;
            if (cs == 0)      wrow = wt + l15 * 128;
            else if (cs == 1) wrow = wp + l15 * 128;
            else              wrow = wg + ((cs - 2) * 16 + l15) * 128;
            short8 bf = ld8(wrow + ks * 32 + lg * 8);
            acc[0][csl] = MFMA16(a[0], bf, acc[0][csl], 0, 0, 0);
            acc[1][csl] = MFMA16(a[1], bf, acc[1][csl], 0, 0, 0);
        }
    }

    const size_t pixb = (size_t)b * 4096 + rp * 128 + h * 32 + p * 16;
#pragma unroll
    for (int csl = 0; csl < 3; csl++) {
        int cs = csbase + csl;
        if (cs == 0) {            // theta: C rows = px-in-chunk
#pragma unroll
            for (int cc = 0; cc < 2; cc++)
#pragma unroll
                for (int r = 0; r < 4; r++)
                    theta_t[(pixb + cc * 64 + lg * 4 + r) * 16 + l15] =
                        f2b(acc[cc][csl][r]);
        } else if (cs == 1) {     // phi pool
#pragma unroll
            for (int h2 = 0; h2 < 2; h2++) {
                float m = max4(acc[0][csl][2 * h2], acc[0][csl][2 * h2 + 1],
                               acc[1][csl][2 * h2], acc[1][csl][2 * h2 + 1]);
                int j = rp * 32 + h * 16 + p * 8 + lg * 2 + h2;
                phi_t[((size_t)b * 1024 + j) * 16 + l15] = f2b(m);
            }
        } else {                  // g pool, blocked layout
            int gcrow = (cs - 2) * 16 + l15;
            float m0 = max4(acc[0][csl][0], acc[0][csl][1], acc[1][csl][0], acc[1][csl][1]);
            float m1 = max4(acc[0][csl][2], acc[0][csl][3], acc[1][csl][2], acc[1][csl][3]);
            int jb = rp * 2 + h, jl = p * 8 + lg * 2;
            *(int*)(g_blk + (((size_t)b * 64 + jb) * 64 + gcrow) * 16 + jl) = pk2(m0, m1);
        }
    }
}

// ---------------------------------------------------------------------------
// K2: attention, re-tiled for occupancy. Block = (b, 32 i's) -> 1024 blocks,
// i-tile == MFMA32 N dim. Wave w = j-quarter: 4 j-tiles of 64 (jt = w*4+t).
// j-loop body identical to the R4/R6-verified version (shift-softmax, S^T via
// MFMA32 K=16 exact, C->B-frag transform via shfl_xor(32) on packed bf16
// pairs, no LDS/barriers in-loop). Epilogue: 4-way partial combine in LDS
// (plain adds -- valid for shift-softmax), then per-wave 32-co slice of the
// fused w_o GEMM + gamma*o + x residual.
// NOTE: private arrays only statically indexed (lam selection via ternaries).
__global__ __launch_bounds__(256) void attn_k(
    const float* __restrict__ x, const short* __restrict__ theta_t,
    const short* __restrict__ phi_t, const short* __restrict__ g_blk,
    const float* __restrict__ wo, const float* __restrict__ gamma_p,
    float* __restrict__ out)
{
    __shared__ float lds[4 * 2 * 16 * 64 + 4 * 64];   // 32 KB partials + 1 KB l
    const int tid = threadIdx.x;
    const int w = tid >> 6, lane = tid & 63, l31 = lane & 31, lam = lane >> 5;
    const int b = blockIdx.x >> 7, i0 = (blockIdx.x & 127) << 5;
    const int i = i0 + l31;

    // persistent theta B-frag: B[n=i][k=c], k = lam*8+q (K=16 exact)
    short8 tb = *(const short8*)(theta_t + ((size_t)b * 4096 + i) * 16 + lam * 8);

    f32x16 acc0, acc1, z16;
#pragma unroll
    for (int r = 0; r < 16; r++) { acc0[r] = 0.f; acc1[r] = 0.f; z16[r] = 0.f; }
    float rs = 0.f;

    for (int t = 0; t < 4; t++) {
        const int jt = w * 4 + t;
        // ---- QK: S^T[64j][32i], rows j = jk*32 + (reg&3)+8*(reg>>2)+4*lam
        f32x16 s0, s1;
        {
            short8 pa0 = *(const short8*)(phi_t + ((size_t)b * 1024 + jt * 64 + l31) * 16 + lam * 8);
            short8 pa1 = *(const short8*)(phi_t + ((size_t)b * 1024 + jt * 64 + 32 + l31) * 16 + lam * 8);
            s0 = MFMA32(pa0, tb, z16, 0, 0, 0);
            s1 = MFMA32(pa1, tb, z16, 0, 0, 0);
        }
        // ---- exp + pack pairs: W[jk*8+rg*2+h] covers j = 32jk+8rg+4lam+2h+{0,1}
        int W[16], X[16];
#pragma unroll
        for (int jk = 0; jk < 2; jk++)
#pragma unroll
            for (int rg = 0; rg < 4; rg++)
#pragma unroll
                for (int h = 0; h < 2; h++) {
                    float p0 = __expf((jk ? s1 : s0)[rg * 4 + 2 * h]     - SHIFT);
                    float p1 = __expf((jk ? s1 : s0)[rg * 4 + 2 * h + 1] - SHIFT);
                    rs += p0 + p1;
                    W[jk * 8 + rg * 2 + h] = pk2(p0, p1);
                }
#pragma unroll
        for (int k = 0; k < 16; k++) X[k] = __shfl_xor(W[k], 32, 64);

        // ---- PV: O^T[c][i] += G^T . P^T ; B-frag(ck): static idx + lam-cndmask
#pragma unroll
        for (int ck = 0; ck < 4; ck++) {
            const int cb2 = (ck >> 1) * 8 + (ck & 1) * 4;
            int4v pi;
            pi.x = lam ? X[cb2 + 2] : W[cb2];
            pi.y = lam ? X[cb2 + 3] : W[cb2 + 1];
            pi.z = lam ? W[cb2 + 2] : X[cb2];
            pi.w = lam ? W[cb2 + 3] : X[cb2 + 1];
            short8 pb = __builtin_bit_cast(short8, pi);
            const short* gp = g_blk + (((size_t)b * 64 + jt * 4 + ck) * 64) * 16;
            short8 ga0 = *(const short8*)(gp + (l31)      * 16 + lam * 8);
            short8 ga1 = *(const short8*)(gp + (32 + l31) * 16 + lam * 8);
            acc0 = MFMA32(ga0, pb, acc0, 0, 0, 0);
            acc1 = MFMA32(ga1, pb, acc1, 0, 0, 0);
        }
    }

    // ---- combine lane halves of row-sum (both halves hold same i=l31)
    rs += __shfl_xor(rs, 32, 64);

    // ---- write partials, one barrier, 4-way j-quarter combine
#pragma unroll
    for (int reg = 0; reg < 16; reg++) {
        lds[((w * 2 + 0) * 16 + reg) * 64 + lane] = acc0[reg];
        lds[((w * 2 + 1) * 16 + reg) * 64 + lane] = acc1[reg];
    }
    lds[8192 + w * 64 + lane] = rs;
    __syncthreads();

    float o[32];
#pragma unroll
    for (int cs2 = 0; cs2 < 2; cs2++)
#pragma unroll
        for (int reg = 0; reg < 16; reg++)
            o[cs2 * 16 + reg] =
                (lds[((0 * 2 + cs2) * 16 + reg) * 64 + lane] +
                 lds[((1 * 2 + cs2) * 16 + reg) * 64 + lane]) +
                (lds[((2 * 2 + cs2) * 16 + reg) * 64 + lane] +
                 lds[((3 * 2 + cs2) * 16 + reg) * 64 + lane]);
    float lf = (lds[8192 + 0 * 64 + lane] + lds[8192 + 1 * 64 + lane]) +
               (lds[8192 + 2 * 64 + lane] + lds[8192 + 3 * 64 + lane]);
    float rinv = 1.0f / lf;
#pragma unroll
    for (int k = 0; k < 32; k++) o[k] *= rinv;

    // pack O^T rows c = cs2*32 + 8rg + 4lam + 2h+{0,1}; exchange lane halves
    int Wo[16], Xo[16];
#pragma unroll
    for (int cs2 = 0; cs2 < 2; cs2++)
#pragma unroll
        for (int rg = 0; rg < 4; rg++)
#pragma unroll
            for (int h = 0; h < 2; h++)
                Wo[cs2 * 8 + rg * 2 + h] =
                    pk2(o[cs2 * 16 + rg * 4 + 2 * h], o[cs2 * 16 + rg * 4 + 2 * h + 1]);
#pragma unroll
    for (int k = 0; k < 16; k++) Xo[k] = __shfl_xor(Wo[k], 32, 64);

    // ---- w_o GEMM: wave w owns co slice [w*32, w*32+32)
    const float gam = gamma_p[0];
    f32x16 oc;
#pragma unroll
    for (int r = 0; r < 16; r++) oc[r] = 0.f;
#pragma unroll
    for (int kc = 0; kc < 4; kc++) {
        const int cb2 = (kc >> 1) * 8 + (kc & 1) * 4;
        int4v pi;
        pi.x = lam ? Xo[cb2 + 2] : Wo[cb2];
        pi.y = lam ? Xo[cb2 + 3] : Wo[cb2 + 1];
        pi.z = lam ? Wo[cb2 + 2] : Xo[cb2];
        pi.w = lam ? Wo[cb2 + 3] : Xo[cb2 + 1];
        short8 ob = __builtin_bit_cast(short8, pi);
        short8 wa = ld8(wo + (size_t)(w * 32 + l31) * 64 + kc * 16 + lam * 8);
        oc = MFMA32(wa, ob, oc, 0, 0, 0);
    }
#pragma unroll
    for (int reg = 0; reg < 16; reg++) {
        int co = w * 32 + (reg & 3) + 8 * (reg >> 2) + 4 * lam;
        size_t idx = ((size_t)b * 128 + co) * HW + i0 + l31;
        out[idx] = gam * oc[reg] + x[idx];
    }
}

// ---------------------------------------------------------------------------
extern "C" void kernel_launch(void* const* d_in, const int* in_sizes, int n_in,
                              void* d_out, int out_size, void* d_ws, size_t ws_size,
                              hipStream_t stream)
{
    const float* x     = (const float*)d_in[0];
    const float* wt    = (const float*)d_in[1];
    const float* wp    = (const float*)d_in[2];
    const float* wg    = (const float*)d_in[3];
    const float* wo    = (const float*)d_in[4];
    const float* gamma = (const float*)d_in[5];
    float* out = (float*)d_out;

    char* ws = (char*)d_ws;
    short* theta_t = (short*)(ws + 0);        // 8*4096*16 sh = 1048576 B
    short* phi_t   = (short*)(ws + 1048576);  // 8*1024*16 sh = 262144 B
    short* g_blk   = (short*)(ws + 1310720);  // 8*64*64*16 sh = 1048576 B
    // total ~2.25 MiB of workspace

    conv_pool<<<512,  256, 0, stream>>>(x, wt, wp, wg, theta_t, phi_t, g_blk);
    attn_k   <<<1024, 256, 0, stream>>>(x, theta_t, phi_t, g_blk, wo, gamma, out);
}